// Round 7
// baseline (17689.856 us; speedup 1.0000x reference)
//
#include <hip/hip_runtime.h>
#include <hip/hip_bf16.h>
#include <math.h>

// LearnablePQ round 5 (third resubmit — rounds 5 and 6 hit
// GPUAcquisitionTimeout, never executed): f32 fast path + margin-gated f64
// fallback.
// Round-4 f64 kernel passed with absmax=0.0 (argmin-flip theory confirmed)
// but ran 4.7ms, latency-bound (VALUBusy 49%, 8 waves/CU). Only ~300 of 1M
// argmin decisions are close enough for f32 noise (~2e-5, worst-case <2e-4)
// to flip. Kernel A: f32 fused MLP+PQ at 16 waves/CU, tracks top-2 distance
// margin; rows with any margin < TAU=4e-3 (>=25x worst-case noise) go to a
// worklist in d_ws. Kernel B: f64 recompute of flagged rows (grid-stride),
// overwrites those output rows. Zero missed flips by construction.

#define IN_DIM 768
#define HD1    512
#define HD2    384
#define TGT    256
#define NSUB   16
#define KCODE  256
#define SUBD   16
#define RPB    16    // rows per block (kernel A)
#define NT_A   512
#define NT_B   256
#define TAU    4e-3f

#define FMA4(ACC, S, W)            \
    ACC.x = fmaf(S, W.x, ACC.x);   \
    ACC.y = fmaf(S, W.y, ACC.y);   \
    ACC.z = fmaf(S, W.z, ACC.z);   \
    ACC.w = fmaf(S, W.w, ACC.w);

__device__ __forceinline__ float gelu32(float v) {
    return 0.5f * v * (1.0f + erff(v * 0.70710678118654752440f));
}
__device__ __forceinline__ double gelu64(double v) {
    return 0.5 * v * (1.0 + erf(v * 0.70710678118654752440084436210485));
}

// ---------------------------------------------------------------------------
// Kernel A: f32 fused MLP + PQ with margin flagging.
// 16 rows/block, 512 threads (8 waves). LDS 56KB -> 2 blocks/CU -> 16 waves/CU.
// ---------------------------------------------------------------------------
__global__ __launch_bounds__(NT_A) void mlp_pq_f32(
    const float* __restrict__ x,
    const float* __restrict__ W1, const float* __restrict__ b1,
    const float* __restrict__ W2, const float* __restrict__ b2,
    const float* __restrict__ W3, const float* __restrict__ b3,
    const float* __restrict__ cbs,
    float* __restrict__ out,
    unsigned* __restrict__ cnt, unsigned* __restrict__ wl, unsigned cap)
{
    // h1 [16][512] f32 = 32KB @0; h2 [16][384] f32 = 24KB @32KB.
    // enc [16][256] f32 = 16KB aliases h1 (h1 dead after GEMM2 reads + barrier).
    __shared__ float lds[RPB * HD1 + RPB * HD2];   // 14336 f = 56KB
    float* h1s  = lds;
    float* h2s  = lds + RPB * HD1;
    float* encs = lds;

    const int t  = threadIdx.x;
    const int rg = t >> 5;      // 16 row groups x 1 row
    const int cg = t & 31;      // 32 col groups
    const size_t row0 = (size_t)blockIdx.x * RPB;

    // ---------- GEMM1: (16x768)@(768x512)+b1, gelu -> h1s ----------
    {
        float4 acc[4];
        #pragma unroll
        for (int q = 0; q < 4; ++q) acc[q] = make_float4(0.f, 0.f, 0.f, 0.f);
        const int c0 = cg << 4;
        const float* xr = x + (row0 + rg) * IN_DIM;
        const float* wp = W1 + c0;
        for (int k = 0; k < IN_DIM; k += 4) {
            float4 a = *(const float4*)(xr + k);
            #pragma unroll
            for (int j = 0; j < 4; ++j) {
                float4 w0 = *(const float4*)(wp);
                float4 w1 = *(const float4*)(wp + 4);
                float4 w2 = *(const float4*)(wp + 8);
                float4 w3 = *(const float4*)(wp + 12);
                float s = ((const float*)&a)[j];
                FMA4(acc[0], s, w0) FMA4(acc[1], s, w1)
                FMA4(acc[2], s, w2) FMA4(acc[3], s, w3)
                wp += HD1;
            }
        }
        #pragma unroll
        for (int q = 0; q < 4; ++q) {
            float4 bb = *(const float4*)(b1 + c0 + (q << 2));
            float4 g;
            g.x = gelu32(acc[q].x + bb.x);
            g.y = gelu32(acc[q].y + bb.y);
            g.z = gelu32(acc[q].z + bb.z);
            g.w = gelu32(acc[q].w + bb.w);
            *(float4*)&h1s[rg * HD1 + c0 + (q << 2)] = g;
        }
    }
    __syncthreads();

    // ---------- GEMM2: (16x512)@(512x384)+b2, gelu -> h2s ----------
    {
        float4 acc[3];
        #pragma unroll
        for (int q = 0; q < 3; ++q) acc[q] = make_float4(0.f, 0.f, 0.f, 0.f);
        const int c0 = cg * 12;
        const float* hr = h1s + rg * HD1;
        const float* wp = W2 + c0;
        for (int k = 0; k < HD1; k += 4) {
            float4 a = *(const float4*)(hr + k);
            #pragma unroll
            for (int j = 0; j < 4; ++j) {
                float4 w0 = *(const float4*)(wp);
                float4 w1 = *(const float4*)(wp + 4);
                float4 w2 = *(const float4*)(wp + 8);
                float s = ((const float*)&a)[j];
                FMA4(acc[0], s, w0) FMA4(acc[1], s, w1) FMA4(acc[2], s, w2)
                wp += HD2;
            }
        }
        #pragma unroll
        for (int q = 0; q < 3; ++q) {
            float4 bb = *(const float4*)(b2 + c0 + (q << 2));
            float4 g;
            g.x = gelu32(acc[q].x + bb.x);
            g.y = gelu32(acc[q].y + bb.y);
            g.z = gelu32(acc[q].z + bb.z);
            g.w = gelu32(acc[q].w + bb.w);
            *(float4*)&h2s[rg * HD2 + c0 + (q << 2)] = g;
        }
    }
    __syncthreads();

    // ---------- GEMM3: (16x384)@(384x256)+b3 -> encs (aliases h1) ----------
    {
        float4 acc[2];
        #pragma unroll
        for (int q = 0; q < 2; ++q) acc[q] = make_float4(0.f, 0.f, 0.f, 0.f);
        const int c0 = cg << 3;
        const float* hr = h2s + rg * HD2;
        const float* wp = W3 + c0;
        for (int k = 0; k < HD2; k += 4) {
            float4 a = *(const float4*)(hr + k);
            #pragma unroll
            for (int j = 0; j < 4; ++j) {
                float4 w0 = *(const float4*)(wp);
                float4 w1 = *(const float4*)(wp + 4);
                float s = ((const float*)&a)[j];
                FMA4(acc[0], s, w0) FMA4(acc[1], s, w1)
                wp += TGT;
            }
        }
        #pragma unroll
        for (int q = 0; q < 2; ++q) {
            float4 bb = *(const float4*)(b3 + c0 + (q << 2));
            float4 e = acc[q];
            e.x += bb.x; e.y += bb.y; e.z += bb.z; e.w += bb.w;
            *(float4*)&encs[rg * TGT + c0 + (q << 2)] = e;
        }
    }
    __syncthreads();

    // ---------- PQ: f32 argmin + top-2 margin, split-k across lane pairs ----
    // r = t>>5 (16 rows), s = (t>>1)&15 (16 subs), half = t&1 (128 codes each)
    {
        const int r = t >> 5;
        const int s = (t >> 1) & 15;
        const int half = t & 1;

        float tv[16];
        const float* ep = encs + r * TGT + s * SUBD;
        #pragma unroll
        for (int d = 0; d < 16; ++d) tv[d] = -2.0f * ep[d];

        const float* cbS = cbs + (size_t)s * KCODE * SUBD;
        const float* cbH = cbS + half * 128 * SUBD;

        // dist_k = sum_d c_d*(c_d - 2 e_d) (e2 dropped: k-independent shift,
        // argmin- and margin-preserving). Strict < = first-index tie-break.
        float l1 = 3.402823466e38f, l2 = 3.402823466e38f;
        int li = 0;
        for (int kk = 0; kk < 128; ++kk) {
            const float4* cp = (const float4*)(cbH + kk * SUBD);
            float4 c0 = cp[0], c1 = cp[1], c2 = cp[2], c3 = cp[3];
            float d0 = c0.x*(c0.x+tv[0]) + c0.y*(c0.y+tv[1]) + c0.z*(c0.z+tv[2]) + c0.w*(c0.w+tv[3]);
            float d1 = c1.x*(c1.x+tv[4]) + c1.y*(c1.y+tv[5]) + c1.z*(c1.z+tv[6]) + c1.w*(c1.w+tv[7]);
            float d2 = c2.x*(c2.x+tv[8]) + c2.y*(c2.y+tv[9]) + c2.z*(c2.z+tv[10]) + c2.w*(c2.w+tv[11]);
            float d3 = c3.x*(c3.x+tv[12]) + c3.y*(c3.y+tv[13]) + c3.z*(c3.z+tv[14]) + c3.w*(c3.w+tv[15]);
            float dist = (d0 + d1) + (d2 + d3);
            if (dist < l1)      { l2 = l1; l1 = dist; li = kk; }
            else if (dist < l2) { l2 = dist; }
        }
        int idx = li + half * 128;

        // combine halves (pair lane t^1): global best/second-best + tie-break
        float o1 = __shfl_xor(l1, 1);
        float o2 = __shfl_xor(l2, 1);
        int   oi = __shfl_xor(idx, 1);
        float g1, g2; int gi;
        if (o1 < l1)      { g1 = o1; gi = oi; g2 = fminf(l1, o2); }
        else if (o1 > l1) { g1 = l1; gi = idx; g2 = fminf(o1, l2); }
        else              { g1 = l1; gi = (oi < idx) ? oi : idx; g2 = l1; } // exact tie -> margin 0

        // flag rows whose margin can't be trusted at f32 noise level
        bool flagged = (g2 - g1) < TAU;
        unsigned long long mask = __ballot(flagged);
        if ((t & 31) == 0) {
            unsigned rm = (unsigned)(mask >> (t & 32));  // this row's 32 bits
            if (rm) {
                unsigned p = atomicAdd(cnt, 1u);
                if (p < cap) wl[p] = (unsigned)(row0 + r);
            }
        }

        // write selected codebook row (f32 bit-exact copy); pair splits 16 floats
        const float4* sp = (const float4*)(cbS + gi * SUBD);
        float* op = out + (row0 + r) * TGT + s * SUBD;
        if (half == 0) {
            ((float4*)op)[0] = sp[0];
            ((float4*)op)[1] = sp[1];
        } else {
            ((float4*)op)[2] = sp[2];
            ((float4*)op)[3] = sp[3];
        }
    }
}

// ---------------------------------------------------------------------------
// Kernel B: f64 recompute of flagged rows. One 256-thread block per row,
// grid-stride over the worklist. Overwrites the full output row.
// ---------------------------------------------------------------------------
__global__ __launch_bounds__(NT_B) void fixup_f64(
    const float* __restrict__ x,
    const float* __restrict__ W1, const float* __restrict__ b1,
    const float* __restrict__ W2, const float* __restrict__ b2,
    const float* __restrict__ W3, const float* __restrict__ b3,
    const float* __restrict__ cbs,
    float* __restrict__ out,
    const unsigned* __restrict__ cnt, const unsigned* __restrict__ wl,
    unsigned cap)
{
    __shared__ double xr[IN_DIM];   // 6KB
    __shared__ double h1[HD1];      // 4KB
    __shared__ double h2[HD2];      // 3KB
    __shared__ double en[TGT];      // 2KB

    const int t = threadIdx.x;
    unsigned n = *cnt;
    if (n > cap) n = cap;

    for (unsigned w = blockIdx.x; w < n; w += gridDim.x) {
        const size_t row = wl[w];
        __syncthreads();   // protect LDS reuse across worklist iterations

        // stage x row as f64
        const float* xp = x + row * IN_DIM;
        xr[t]       = (double)xp[t];
        xr[t + 256] = (double)xp[t + 256];
        xr[t + 512] = (double)xp[t + 512];
        __syncthreads();

        // h1: 512 cols, 2 per thread
        {
            double a0 = 0.0, a1 = 0.0;
            for (int k = 0; k < IN_DIM; ++k) {
                double xv = xr[k];
                a0 = fma(xv, (double)W1[k * HD1 + t], a0);
                a1 = fma(xv, (double)W1[k * HD1 + t + 256], a1);
            }
            h1[t]       = gelu64(a0 + (double)b1[t]);
            h1[t + 256] = gelu64(a1 + (double)b1[t + 256]);
        }
        __syncthreads();

        // h2: 384 cols, threads 0..191 do 2 each
        if (t < 192) {
            double a0 = 0.0, a1 = 0.0;
            for (int k = 0; k < HD1; ++k) {
                double hv = h1[k];
                a0 = fma(hv, (double)W2[k * HD2 + t], a0);
                a1 = fma(hv, (double)W2[k * HD2 + t + 192], a1);
            }
            h2[t]       = gelu64(a0 + (double)b2[t]);
            h2[t + 192] = gelu64(a1 + (double)b2[t + 192]);
        }
        __syncthreads();

        // encoded: 256 cols, 1 per thread
        {
            double a0 = 0.0;
            for (int k = 0; k < HD2; ++k)
                a0 = fma(h2[k], (double)W3[k * TGT + t], a0);
            en[t] = a0 + (double)b3[t];
        }
        __syncthreads();

        // PQ: sub s = t>>4, lane c16 = t&15 scans codes [c16*16, c16*16+16)
        {
            const int s = t >> 4;
            const int c16 = t & 15;
            double e[16];
            #pragma unroll
            for (int d = 0; d < 16; ++d) e[d] = en[s * SUBD + d];

            const float* cbS = cbs + (size_t)s * KCODE * SUBD;
            const float* cbL = cbS + (c16 * 16) * SUBD;

            double best = 1.0e300;
            int bi = c16 * 16;
            for (int kk = 0; kk < 16; ++kk) {
                const float4* cp = (const float4*)(cbL + kk * SUBD);
                float4 c0 = cp[0], c1 = cp[1], c2 = cp[2], c3 = cp[3];
                double dist = 0.0, dd;
                dd = (double)c0.x - e[0];  dist = fma(dd, dd, dist);
                dd = (double)c0.y - e[1];  dist = fma(dd, dd, dist);
                dd = (double)c0.z - e[2];  dist = fma(dd, dd, dist);
                dd = (double)c0.w - e[3];  dist = fma(dd, dd, dist);
                dd = (double)c1.x - e[4];  dist = fma(dd, dd, dist);
                dd = (double)c1.y - e[5];  dist = fma(dd, dd, dist);
                dd = (double)c1.z - e[6];  dist = fma(dd, dd, dist);
                dd = (double)c1.w - e[7];  dist = fma(dd, dd, dist);
                dd = (double)c2.x - e[8];  dist = fma(dd, dd, dist);
                dd = (double)c2.y - e[9];  dist = fma(dd, dd, dist);
                dd = (double)c2.z - e[10]; dist = fma(dd, dd, dist);
                dd = (double)c2.w - e[11]; dist = fma(dd, dd, dist);
                dd = (double)c3.x - e[12]; dist = fma(dd, dd, dist);
                dd = (double)c3.y - e[13]; dist = fma(dd, dd, dist);
                dd = (double)c3.z - e[14]; dist = fma(dd, dd, dist);
                dd = (double)c3.w - e[15]; dist = fma(dd, dd, dist);
                if (dist < best) { best = dist; bi = c16 * 16 + kk; }
            }
            // reduce over the 16 lanes of this sub (xor butterfly, stays in group)
            #pragma unroll
            for (int off = 1; off < 16; off <<= 1) {
                double od = __shfl_xor(best, off);
                int    oi = __shfl_xor(bi, off);
                if (od < best || (od == best && oi < bi)) { best = od; bi = oi; }
            }
            // lanes 0..3 of the group write the winning codebook row
            if (c16 < 4) {
                float4 v = ((const float4*)(cbS + bi * SUBD))[c16];
                ((float4*)(out + row * TGT + s * SUBD))[c16] = v;
            }
        }
    }
}

extern "C" void kernel_launch(void* const* d_in, const int* in_sizes, int n_in,
                              void* d_out, int out_size, void* d_ws, size_t ws_size,
                              hipStream_t stream) {
    const float* x   = (const float*)d_in[0];
    const float* W1  = (const float*)d_in[1];
    const float* b1  = (const float*)d_in[2];
    const float* W2  = (const float*)d_in[3];
    const float* b2  = (const float*)d_in[4];
    const float* W3  = (const float*)d_in[5];
    const float* b3  = (const float*)d_in[6];
    const float* cbs = (const float*)d_in[7];
    float* out = (float*)d_out;

    const int B = in_sizes[0] / IN_DIM;   // 65536
    unsigned* cnt = (unsigned*)d_ws;
    unsigned* wl  = cnt + 1;
    size_t cap_sz = (ws_size / sizeof(unsigned)) - 1;
    unsigned cap = (unsigned)(cap_sz > 65536 ? 65536 : cap_sz);

    hipMemsetAsync(d_ws, 0, sizeof(unsigned), stream);  // zero the counter
    hipLaunchKernelGGL(mlp_pq_f32, dim3(B / RPB), dim3(NT_A), 0, stream,
                       x, W1, b1, W2, b2, W3, b3, cbs, out, cnt, wl, cap);
    hipLaunchKernelGGL(fixup_f64, dim3(2048), dim3(NT_B), 0, stream,
                       x, W1, b1, W2, b2, W3, b3, cbs, out, cnt, wl, cap);
}

// Round 11
// 10995.299 us; speedup vs baseline: 1.6089x; 1.6089x over previous
//
#include <hip/hip_runtime.h>
#include <hip/hip_bf16.h>
#include <math.h>

// LearnablePQ round 8 (third resubmit — rounds 8, 9, 10 all hit
// GPUAcquisitionTimeout; this source has never executed): f32 fast path
// (4r x 4c register tile) + margin-gated f64 fallback, re-tuned from
// round-7 counters.
// Round-7 post-mortem: (1) A was load-bound (1 FMA/W-float, VALUBusy 10.6%)
// -> 4-row W reuse per thread (proven in the round-4 f64 kernel, VALUBusy 49%).
// (2) typical top-2 margin is ~0.016 (codebooks 0.1-scale, encoded ~0.06/dim)
// so TAU=4e-3 flagged ~87% of rows -> TAU=2e-4 (>=7x worst-case f32-vs-f64
// margin noise ~2.7e-5, flags ~15-20% of rows). (3) B was latency-serial
// (~50-100us/row) -> 4-way k-chunked independent accumulator chains.

#define IN_DIM 768
#define HD1    512
#define HD2    384
#define TGT    256
#define NSUB   16
#define KCODE  256
#define SUBD   16
#define RPB    16    // rows per block (kernel A)
#define NT_A   512
#define NT_B   256
#define TAU    2e-4f

__device__ __forceinline__ float gelu32(float v) {
    return 0.5f * v * (1.0f + erff(v * 0.70710678118654752440f));
}
__device__ __forceinline__ double gelu64(double v) {
    return 0.5 * v * (1.0 + erf(v * 0.70710678118654752440084436210485));
}

// ---------------------------------------------------------------------------
// Kernel A: f32 fused MLP + PQ with margin flagging. 16 rows/block, 512 thr
// (8 waves), LDS 56KB -> 2 blocks/CU -> 16 waves/CU. Thread GEMM tiles:
// GEMM1 4rx4c, GEMM2 4rx3c, GEMM3 4rx2c (W-load reused across 4 rows).
// ---------------------------------------------------------------------------
__global__ __launch_bounds__(NT_A) void mlp_pq_f32(
    const float* __restrict__ x,
    const float* __restrict__ W1, const float* __restrict__ b1,
    const float* __restrict__ W2, const float* __restrict__ b2,
    const float* __restrict__ W3, const float* __restrict__ b3,
    const float* __restrict__ cbs,
    float* __restrict__ out,
    unsigned* __restrict__ cnt, unsigned* __restrict__ wl, unsigned cap)
{
    // h1 [16][512] f32 = 32KB @0; h2 [16][384] f32 = 24KB @32KB.
    // enc [16][256] f32 = 16KB aliases h1 (h1 dead after GEMM2 reads+barrier).
    __shared__ float lds[RPB * HD1 + RPB * HD2];   // 14336 f = 56KB
    float* h1s  = lds;
    float* h2s  = lds + RPB * HD1;
    float* encs = lds;

    const int t  = threadIdx.x;
    const int rg = t >> 7;      // 4 row groups x 4 rows (wave-uniform)
    const int cg = t & 127;     // 128 col groups
    const int r0 = rg << 2;
    const size_t row0 = (size_t)blockIdx.x * RPB;

    // ---------- GEMM1: (16x768)@(768x512)+b1, gelu -> h1s ----------
    {
        const int c0 = cg << 2;
        float acc[4][4];
        #pragma unroll
        for (int j = 0; j < 4; ++j)
            #pragma unroll
            for (int c = 0; c < 4; ++c) acc[j][c] = 0.f;

        const float* xr0 = x + (row0 + r0) * IN_DIM;
        const float* xr1 = xr0 + IN_DIM;
        const float* xr2 = xr1 + IN_DIM;
        const float* xr3 = xr2 + IN_DIM;
        const float* wp  = W1 + c0;

        for (int k = 0; k < IN_DIM; k += 4) {
            float4 a0 = *(const float4*)(xr0 + k);
            float4 a1 = *(const float4*)(xr1 + k);
            float4 a2 = *(const float4*)(xr2 + k);
            float4 a3 = *(const float4*)(xr3 + k);
            #pragma unroll
            for (int kk = 0; kk < 4; ++kk) {
                float4 w = *(const float4*)(wp);
                wp += HD1;
                float av0 = ((const float*)&a0)[kk];
                float av1 = ((const float*)&a1)[kk];
                float av2 = ((const float*)&a2)[kk];
                float av3 = ((const float*)&a3)[kk];
                acc[0][0] = fmaf(av0, w.x, acc[0][0]); acc[0][1] = fmaf(av0, w.y, acc[0][1]);
                acc[0][2] = fmaf(av0, w.z, acc[0][2]); acc[0][3] = fmaf(av0, w.w, acc[0][3]);
                acc[1][0] = fmaf(av1, w.x, acc[1][0]); acc[1][1] = fmaf(av1, w.y, acc[1][1]);
                acc[1][2] = fmaf(av1, w.z, acc[1][2]); acc[1][3] = fmaf(av1, w.w, acc[1][3]);
                acc[2][0] = fmaf(av2, w.x, acc[2][0]); acc[2][1] = fmaf(av2, w.y, acc[2][1]);
                acc[2][2] = fmaf(av2, w.z, acc[2][2]); acc[2][3] = fmaf(av2, w.w, acc[2][3]);
                acc[3][0] = fmaf(av3, w.x, acc[3][0]); acc[3][1] = fmaf(av3, w.y, acc[3][1]);
                acc[3][2] = fmaf(av3, w.z, acc[3][2]); acc[3][3] = fmaf(av3, w.w, acc[3][3]);
            }
        }
        float4 bb = *(const float4*)(b1 + c0);
        #pragma unroll
        for (int j = 0; j < 4; ++j) {
            float4 g;
            g.x = gelu32(acc[j][0] + bb.x);
            g.y = gelu32(acc[j][1] + bb.y);
            g.z = gelu32(acc[j][2] + bb.z);
            g.w = gelu32(acc[j][3] + bb.w);
            *(float4*)&h1s[(r0 + j) * HD1 + c0] = g;
        }
    }
    __syncthreads();

    // ---------- GEMM2: (16x512)@(512x384)+b2, gelu -> h2s ----------
    {
        const int c0 = cg * 3;
        float acc[4][3];
        #pragma unroll
        for (int j = 0; j < 4; ++j)
            #pragma unroll
            for (int c = 0; c < 3; ++c) acc[j][c] = 0.f;

        const float* hr0 = h1s + r0 * HD1;
        const float* hr1 = hr0 + HD1;
        const float* hr2 = hr1 + HD1;
        const float* hr3 = hr2 + HD1;
        const float* wp  = W2 + c0;

        for (int k = 0; k < HD1; k += 4) {
            float4 a0 = *(const float4*)(hr0 + k);
            float4 a1 = *(const float4*)(hr1 + k);
            float4 a2 = *(const float4*)(hr2 + k);
            float4 a3 = *(const float4*)(hr3 + k);
            #pragma unroll
            for (int kk = 0; kk < 4; ++kk) {
                float w0 = wp[0], w1 = wp[1], w2 = wp[2];
                wp += HD2;
                float av0 = ((const float*)&a0)[kk];
                float av1 = ((const float*)&a1)[kk];
                float av2 = ((const float*)&a2)[kk];
                float av3 = ((const float*)&a3)[kk];
                acc[0][0] = fmaf(av0, w0, acc[0][0]); acc[0][1] = fmaf(av0, w1, acc[0][1]); acc[0][2] = fmaf(av0, w2, acc[0][2]);
                acc[1][0] = fmaf(av1, w0, acc[1][0]); acc[1][1] = fmaf(av1, w1, acc[1][1]); acc[1][2] = fmaf(av1, w2, acc[1][2]);
                acc[2][0] = fmaf(av2, w0, acc[2][0]); acc[2][1] = fmaf(av2, w1, acc[2][1]); acc[2][2] = fmaf(av2, w2, acc[2][2]);
                acc[3][0] = fmaf(av3, w0, acc[3][0]); acc[3][1] = fmaf(av3, w1, acc[3][1]); acc[3][2] = fmaf(av3, w2, acc[3][2]);
            }
        }
        float b0 = b2[c0], b1v = b2[c0 + 1], b2v = b2[c0 + 2];
        #pragma unroll
        for (int j = 0; j < 4; ++j) {
            h2s[(r0 + j) * HD2 + c0    ] = gelu32(acc[j][0] + b0);
            h2s[(r0 + j) * HD2 + c0 + 1] = gelu32(acc[j][1] + b1v);
            h2s[(r0 + j) * HD2 + c0 + 2] = gelu32(acc[j][2] + b2v);
        }
    }
    __syncthreads();

    // ---------- GEMM3: (16x384)@(384x256)+b3 -> encs (aliases h1) ----------
    {
        const int c0 = cg << 1;
        float acc[4][2];
        #pragma unroll
        for (int j = 0; j < 4; ++j)
            #pragma unroll
            for (int c = 0; c < 2; ++c) acc[j][c] = 0.f;

        const float* hr0 = h2s + r0 * HD2;
        const float* hr1 = hr0 + HD2;
        const float* hr2 = hr1 + HD2;
        const float* hr3 = hr2 + HD2;
        const float* wp  = W3 + c0;

        for (int k = 0; k < HD2; k += 4) {
            float4 a0 = *(const float4*)(hr0 + k);
            float4 a1 = *(const float4*)(hr1 + k);
            float4 a2 = *(const float4*)(hr2 + k);
            float4 a3 = *(const float4*)(hr3 + k);
            #pragma unroll
            for (int kk = 0; kk < 4; ++kk) {
                float w0 = wp[0], w1 = wp[1];
                wp += TGT;
                float av0 = ((const float*)&a0)[kk];
                float av1 = ((const float*)&a1)[kk];
                float av2 = ((const float*)&a2)[kk];
                float av3 = ((const float*)&a3)[kk];
                acc[0][0] = fmaf(av0, w0, acc[0][0]); acc[0][1] = fmaf(av0, w1, acc[0][1]);
                acc[1][0] = fmaf(av1, w0, acc[1][0]); acc[1][1] = fmaf(av1, w1, acc[1][1]);
                acc[2][0] = fmaf(av2, w0, acc[2][0]); acc[2][1] = fmaf(av2, w1, acc[2][1]);
                acc[3][0] = fmaf(av3, w0, acc[3][0]); acc[3][1] = fmaf(av3, w1, acc[3][1]);
            }
        }
        float b0 = b3[c0], b1v = b3[c0 + 1];
        #pragma unroll
        for (int j = 0; j < 4; ++j) {
            encs[(r0 + j) * TGT + c0    ] = acc[j][0] + b0;
            encs[(r0 + j) * TGT + c0 + 1] = acc[j][1] + b1v;
        }
    }
    __syncthreads();

    // ---------- PQ: f32 argmin + top-2 margin, split-k across lane pairs ----
    // r = t>>5 (16 rows), s = (t>>1)&15 (16 subs), half = t&1 (128 codes each)
    // (identical to round-7 proven logic; only TAU changed)
    {
        const int r = t >> 5;
        const int s = (t >> 1) & 15;
        const int half = t & 1;

        float tv[16];
        const float* ep = encs + r * TGT + s * SUBD;
        #pragma unroll
        for (int d = 0; d < 16; ++d) tv[d] = -2.0f * ep[d];

        const float* cbS = cbs + (size_t)s * KCODE * SUBD;
        const float* cbH = cbS + half * 128 * SUBD;

        // dist_k = sum_d c_d*(c_d - 2 e_d) (e2 dropped: k-independent shift,
        // argmin- and margin-preserving). Strict < = first-index tie-break.
        float l1 = 3.402823466e38f, l2 = 3.402823466e38f;
        int li = 0;
        for (int kk = 0; kk < 128; ++kk) {
            const float4* cp = (const float4*)(cbH + kk * SUBD);
            float4 c0 = cp[0], c1 = cp[1], c2 = cp[2], c3 = cp[3];
            float d0 = c0.x*(c0.x+tv[0]) + c0.y*(c0.y+tv[1]) + c0.z*(c0.z+tv[2]) + c0.w*(c0.w+tv[3]);
            float d1 = c1.x*(c1.x+tv[4]) + c1.y*(c1.y+tv[5]) + c1.z*(c1.z+tv[6]) + c1.w*(c1.w+tv[7]);
            float d2 = c2.x*(c2.x+tv[8]) + c2.y*(c2.y+tv[9]) + c2.z*(c2.z+tv[10]) + c2.w*(c2.w+tv[11]);
            float d3 = c3.x*(c3.x+tv[12]) + c3.y*(c3.y+tv[13]) + c3.z*(c3.z+tv[14]) + c3.w*(c3.w+tv[15]);
            float dist = (d0 + d1) + (d2 + d3);
            if (dist < l1)      { l2 = l1; l1 = dist; li = kk; }
            else if (dist < l2) { l2 = dist; }
        }
        int idx = li + half * 128;

        // combine halves (pair lane t^1): global best/second-best + tie-break
        float o1 = __shfl_xor(l1, 1);
        float o2 = __shfl_xor(l2, 1);
        int   oi = __shfl_xor(idx, 1);
        float g1, g2; int gi;
        if (o1 < l1)      { g1 = o1; gi = oi; g2 = fminf(l1, o2); }
        else if (o1 > l1) { g1 = l1; gi = idx; g2 = fminf(o1, l2); }
        else              { g1 = l1; gi = (oi < idx) ? oi : idx; g2 = l1; } // exact tie -> margin 0

        // flag rows whose margin can't be trusted at f32 noise level
        bool flagged = (g2 - g1) < TAU;
        unsigned long long mask = __ballot(flagged);
        if ((t & 31) == 0) {
            unsigned rm = (unsigned)(mask >> (t & 32));  // this row's 32 bits
            if (rm) {
                unsigned p = atomicAdd(cnt, 1u);
                if (p < cap) wl[p] = (unsigned)(row0 + r);
            }
        }

        // write selected codebook row (f32 bit-exact copy); pair splits 16 floats
        const float4* sp = (const float4*)(cbS + gi * SUBD);
        float* op = out + (row0 + r) * TGT + s * SUBD;
        if (half == 0) {
            ((float4*)op)[0] = sp[0];
            ((float4*)op)[1] = sp[1];
        } else {
            ((float4*)op)[2] = sp[2];
            ((float4*)op)[3] = sp[3];
        }
    }
}

// ---------------------------------------------------------------------------
// Kernel B: f64 recompute of flagged rows, 4-way k-chunked ILP (8 independent
// load+fma chains per thread). One 256-thread block per row, grid-stride.
// ---------------------------------------------------------------------------
__global__ __launch_bounds__(NT_B) void fixup_f64(
    const float* __restrict__ x,
    const float* __restrict__ W1, const float* __restrict__ b1,
    const float* __restrict__ W2, const float* __restrict__ b2,
    const float* __restrict__ W3, const float* __restrict__ b3,
    const float* __restrict__ cbs,
    float* __restrict__ out,
    const unsigned* __restrict__ cnt, const unsigned* __restrict__ wl,
    unsigned cap)
{
    __shared__ double xr[IN_DIM];   // 6KB
    __shared__ double h1[HD1];      // 4KB
    __shared__ double h2[HD2];      // 3KB
    __shared__ double en[TGT];      // 2KB

    const int t = threadIdx.x;
    unsigned n = *cnt;
    if (n > cap) n = cap;

    for (unsigned w = blockIdx.x; w < n; w += gridDim.x) {
        const size_t row = wl[w];
        __syncthreads();   // protect LDS reuse across worklist iterations

        // stage x row as f64
        const float* xp = x + row * IN_DIM;
        xr[t]       = (double)xp[t];
        xr[t + 256] = (double)xp[t + 256];
        xr[t + 512] = (double)xp[t + 512];
        __syncthreads();

        // h1: cols t, t+256; k split into 4 chunks of 192 (8 indep chains)
        {
            double s0[4], s1[4];
            #pragma unroll
            for (int q = 0; q < 4; ++q) { s0[q] = 0.0; s1[q] = 0.0; }
            for (int kq = 0; kq < 192; ++kq) {
                #pragma unroll
                for (int q = 0; q < 4; ++q) {
                    int k = kq + q * 192;
                    double xv = xr[k];
                    s0[q] = fma(xv, (double)W1[k * HD1 + t],       s0[q]);
                    s1[q] = fma(xv, (double)W1[k * HD1 + t + 256], s1[q]);
                }
            }
            h1[t]       = gelu64(((s0[0] + s0[1]) + (s0[2] + s0[3])) + (double)b1[t]);
            h1[t + 256] = gelu64(((s1[0] + s1[1]) + (s1[2] + s1[3])) + (double)b1[t + 256]);
        }
        __syncthreads();

        // h2: cols t, t+192 for t<192; k split 4 x 128
        if (t < 192) {
            double s0[4], s1[4];
            #pragma unroll
            for (int q = 0; q < 4; ++q) { s0[q] = 0.0; s1[q] = 0.0; }
            for (int kq = 0; kq < 128; ++kq) {
                #pragma unroll
                for (int q = 0; q < 4; ++q) {
                    int k = kq + q * 128;
                    double hv = h1[k];
                    s0[q] = fma(hv, (double)W2[k * HD2 + t],       s0[q]);
                    s1[q] = fma(hv, (double)W2[k * HD2 + t + 192], s1[q]);
                }
            }
            h2[t]       = gelu64(((s0[0] + s0[1]) + (s0[2] + s0[3])) + (double)b2[t]);
            h2[t + 192] = gelu64(((s1[0] + s1[1]) + (s1[2] + s1[3])) + (double)b2[t + 192]);
        }
        __syncthreads();

        // encoded: col t; k split 4 x 96
        {
            double s0[4];
            #pragma unroll
            for (int q = 0; q < 4; ++q) s0[q] = 0.0;
            for (int kq = 0; kq < 96; ++kq) {
                #pragma unroll
                for (int q = 0; q < 4; ++q) {
                    int k = kq + q * 96;
                    s0[q] = fma(h2[k], (double)W3[k * TGT + t], s0[q]);
                }
            }
            en[t] = ((s0[0] + s0[1]) + (s0[2] + s0[3])) + (double)b3[t];
        }
        __syncthreads();

        // PQ: sub s = t>>4, lane c16 = t&15 scans codes [c16*16, c16*16+16)
        {
            const int s = t >> 4;
            const int c16 = t & 15;
            double e[16];
            #pragma unroll
            for (int d = 0; d < 16; ++d) e[d] = en[s * SUBD + d];

            const float* cbS = cbs + (size_t)s * KCODE * SUBD;
            const float* cbL = cbS + (c16 * 16) * SUBD;

            double best = 1.0e300;
            int bi = c16 * 16;
            for (int kk = 0; kk < 16; ++kk) {
                const float4* cp = (const float4*)(cbL + kk * SUBD);
                float4 c0 = cp[0], c1 = cp[1], c2 = cp[2], c3 = cp[3];
                double dist = 0.0, dd;
                dd = (double)c0.x - e[0];  dist = fma(dd, dd, dist);
                dd = (double)c0.y - e[1];  dist = fma(dd, dd, dist);
                dd = (double)c0.z - e[2];  dist = fma(dd, dd, dist);
                dd = (double)c0.w - e[3];  dist = fma(dd, dd, dist);
                dd = (double)c1.x - e[4];  dist = fma(dd, dd, dist);
                dd = (double)c1.y - e[5];  dist = fma(dd, dd, dist);
                dd = (double)c1.z - e[6];  dist = fma(dd, dd, dist);
                dd = (double)c1.w - e[7];  dist = fma(dd, dd, dist);
                dd = (double)c2.x - e[8];  dist = fma(dd, dd, dist);
                dd = (double)c2.y - e[9];  dist = fma(dd, dd, dist);
                dd = (double)c2.z - e[10]; dist = fma(dd, dd, dist);
                dd = (double)c2.w - e[11]; dist = fma(dd, dd, dist);
                dd = (double)c3.x - e[12]; dist = fma(dd, dd, dist);
                dd = (double)c3.y - e[13]; dist = fma(dd, dd, dist);
                dd = (double)c3.z - e[14]; dist = fma(dd, dd, dist);
                dd = (double)c3.w - e[15]; dist = fma(dd, dd, dist);
                if (dist < best) { best = dist; bi = c16 * 16 + kk; }
            }
            // reduce over the 16 lanes of this sub (xor butterfly, stays in group)
            #pragma unroll
            for (int off = 1; off < 16; off <<= 1) {
                double od = __shfl_xor(best, off);
                int    oi = __shfl_xor(bi, off);
                if (od < best || (od == best && oi < bi)) { best = od; bi = oi; }
            }
            // lanes 0..3 of the group write the winning codebook row
            if (c16 < 4) {
                float4 v = ((const float4*)(cbS + bi * SUBD))[c16];
                ((float4*)(out + row * TGT + s * SUBD))[c16] = v;
            }
        }
    }
}

extern "C" void kernel_launch(void* const* d_in, const int* in_sizes, int n_in,
                              void* d_out, int out_size, void* d_ws, size_t ws_size,
                              hipStream_t stream) {
    const float* x   = (const float*)d_in[0];
    const float* W1  = (const float*)d_in[1];
    const float* b1  = (const float*)d_in[2];
    const float* W2  = (const float*)d_in[3];
    const float* b2  = (const float*)d_in[4];
    const float* W3  = (const float*)d_in[5];
    const float* b3  = (const float*)d_in[6];
    const float* cbs = (const float*)d_in[7];
    float* out = (float*)d_out;

    const int B = in_sizes[0] / IN_DIM;   // 65536
    unsigned* cnt = (unsigned*)d_ws;
    unsigned* wl  = cnt + 1;
    size_t cap_sz = (ws_size / sizeof(unsigned)) - 1;
    unsigned cap = (unsigned)(cap_sz > 65536 ? 65536 : cap_sz);

    hipMemsetAsync(d_ws, 0, sizeof(unsigned), stream);  // zero the counter
    hipLaunchKernelGGL(mlp_pq_f32, dim3(B / RPB), dim3(NT_A), 0, stream,
                       x, W1, b1, W2, b2, W3, b3, cbs, out, cnt, wl, cap);
    hipLaunchKernelGGL(fixup_f64, dim3(2048), dim3(NT_B), 0, stream,
                       x, W1, b1, W2, b2, W3, b3, cbs, out, cnt, wl, cap);
}

// Round 12
// 5496.653 us; speedup vs baseline: 3.2183x; 2.0004x over previous
//
#include <hip/hip_runtime.h>
#include <hip/hip_bf16.h>
#include <math.h>

// LearnablePQ round 12.
// Round-11 post-mortem (total 11.0ms, absmax=0):
//  - B (6.9ms): one block per flagged row -> 1 FMA per W-float, 41GB L2
//    traffic, VALUBusy 11.6%. WRITE_SIZE => ~15K flagged rows (23%).
//    FIX: B = round-4's proven f64 batch kernel (8 rows/block, 4-row W
//    reuse, VALU 49%) with worklist row-gather. Arithmetic bit-identical
//    to round 4 (which scored absmax=0 on ALL rows).
//  - A (~4.1ms vs 0.57ms FMA floor): k-loop is load->wait->FMA serial
//    (~40% ceiling). FIX: software-pipeline (register double-buffer) the
//    8 loads one iteration ahead. FMA order unchanged.
// Gate: TAU=2e-4 proven safe (absmax=0) at ~23% flag rate; unchanged.

#define IN_DIM 768
#define HD1    512
#define HD2    384
#define TGT    256
#define NSUB   16
#define KCODE  256
#define SUBD   16
#define RPB    16    // rows per block (kernel A)
#define RPB_B  8     // rows per block (kernel B)
#define NT_A   512
#define NT_B   256
#define TAU    2e-4f

__device__ __forceinline__ float gelu32(float v) {
    return 0.5f * v * (1.0f + erff(v * 0.70710678118654752440f));
}
__device__ __forceinline__ double gelu64(double v) {
    return 0.5 * v * (1.0 + erf(v * 0.70710678118654752440084436210485));
}

// 16 FMAs: 4 rows x 4 cols, W as float4
#define MAC1(AX0, AX1, AX2, AX3, W)                                               \
    acc[0][0] = fmaf(AX0, (W).x, acc[0][0]); acc[0][1] = fmaf(AX0, (W).y, acc[0][1]); \
    acc[0][2] = fmaf(AX0, (W).z, acc[0][2]); acc[0][3] = fmaf(AX0, (W).w, acc[0][3]); \
    acc[1][0] = fmaf(AX1, (W).x, acc[1][0]); acc[1][1] = fmaf(AX1, (W).y, acc[1][1]); \
    acc[1][2] = fmaf(AX1, (W).z, acc[1][2]); acc[1][3] = fmaf(AX1, (W).w, acc[1][3]); \
    acc[2][0] = fmaf(AX2, (W).x, acc[2][0]); acc[2][1] = fmaf(AX2, (W).y, acc[2][1]); \
    acc[2][2] = fmaf(AX2, (W).z, acc[2][2]); acc[2][3] = fmaf(AX2, (W).w, acc[2][3]); \
    acc[3][0] = fmaf(AX3, (W).x, acc[3][0]); acc[3][1] = fmaf(AX3, (W).y, acc[3][1]); \
    acc[3][2] = fmaf(AX3, (W).z, acc[3][2]); acc[3][3] = fmaf(AX3, (W).w, acc[3][3]);

// 12 FMAs: 4 rows x 3 cols, W as 3 scalars
#define MAC2(AX0, AX1, AX2, AX3, W0, W1, W2)                                      \
    acc[0][0] = fmaf(AX0, W0, acc[0][0]); acc[0][1] = fmaf(AX0, W1, acc[0][1]); acc[0][2] = fmaf(AX0, W2, acc[0][2]); \
    acc[1][0] = fmaf(AX1, W0, acc[1][0]); acc[1][1] = fmaf(AX1, W1, acc[1][1]); acc[1][2] = fmaf(AX1, W2, acc[1][2]); \
    acc[2][0] = fmaf(AX2, W0, acc[2][0]); acc[2][1] = fmaf(AX2, W1, acc[2][1]); acc[2][2] = fmaf(AX2, W2, acc[2][2]); \
    acc[3][0] = fmaf(AX3, W0, acc[3][0]); acc[3][1] = fmaf(AX3, W1, acc[3][1]); acc[3][2] = fmaf(AX3, W2, acc[3][2]);

// 8 FMAs: 4 rows x 2 cols
#define MAC3(AX0, AX1, AX2, AX3, W0, W1)                                          \
    acc[0][0] = fmaf(AX0, W0, acc[0][0]); acc[0][1] = fmaf(AX0, W1, acc[0][1]);   \
    acc[1][0] = fmaf(AX1, W0, acc[1][0]); acc[1][1] = fmaf(AX1, W1, acc[1][1]);   \
    acc[2][0] = fmaf(AX2, W0, acc[2][0]); acc[2][1] = fmaf(AX2, W1, acc[2][1]);   \
    acc[3][0] = fmaf(AX3, W0, acc[3][0]); acc[3][1] = fmaf(AX3, W1, acc[3][1]);

// ---------------------------------------------------------------------------
// Kernel A: f32 fused MLP + PQ with margin flagging, software-pipelined k-loops.
// 16 rows/block, 512 thr, LDS 56KB -> 2 blocks/CU -> 16 waves/CU.
// ---------------------------------------------------------------------------
__global__ __launch_bounds__(NT_A) void mlp_pq_f32(
    const float* __restrict__ x,
    const float* __restrict__ W1, const float* __restrict__ b1,
    const float* __restrict__ W2, const float* __restrict__ b2,
    const float* __restrict__ W3, const float* __restrict__ b3,
    const float* __restrict__ cbs,
    float* __restrict__ out,
    unsigned* __restrict__ cnt, unsigned* __restrict__ wl, unsigned cap)
{
    __shared__ float lds[RPB * HD1 + RPB * HD2];   // 56KB
    float* h1s  = lds;
    float* h2s  = lds + RPB * HD1;
    float* encs = lds;   // aliases h1 (dead after GEMM2 reads + barrier)

    const int t  = threadIdx.x;
    const int rg = t >> 7;      // 4 row groups x 4 rows
    const int cg = t & 127;     // 128 col groups
    const int r0 = rg << 2;
    const size_t row0 = (size_t)blockIdx.x * RPB;

    // ---------- GEMM1: (16x768)@(768x512)+b1, gelu -> h1s ----------
    {
        const int c0 = cg << 2;
        float acc[4][4];
        #pragma unroll
        for (int j = 0; j < 4; ++j)
            #pragma unroll
            for (int c = 0; c < 4; ++c) acc[j][c] = 0.f;

        const float* xr0 = x + (row0 + r0) * IN_DIM;
        const float* xr1 = xr0 + IN_DIM;
        const float* xr2 = xr1 + IN_DIM;
        const float* xr3 = xr2 + IN_DIM;
        const float* wp  = W1 + c0;

        float4 a0 = *(const float4*)(xr0);
        float4 a1 = *(const float4*)(xr1);
        float4 a2 = *(const float4*)(xr2);
        float4 a3 = *(const float4*)(xr3);
        float4 w0 = *(const float4*)(wp);
        float4 w1 = *(const float4*)(wp + HD1);
        float4 w2 = *(const float4*)(wp + 2 * HD1);
        float4 w3 = *(const float4*)(wp + 3 * HD1);

        for (int k = 4; k < IN_DIM; k += 4) {
            wp += 4 * HD1;
            float4 a0n = *(const float4*)(xr0 + k);
            float4 a1n = *(const float4*)(xr1 + k);
            float4 a2n = *(const float4*)(xr2 + k);
            float4 a3n = *(const float4*)(xr3 + k);
            float4 w0n = *(const float4*)(wp);
            float4 w1n = *(const float4*)(wp + HD1);
            float4 w2n = *(const float4*)(wp + 2 * HD1);
            float4 w3n = *(const float4*)(wp + 3 * HD1);
            MAC1(a0.x, a1.x, a2.x, a3.x, w0)
            MAC1(a0.y, a1.y, a2.y, a3.y, w1)
            MAC1(a0.z, a1.z, a2.z, a3.z, w2)
            MAC1(a0.w, a1.w, a2.w, a3.w, w3)
            a0 = a0n; a1 = a1n; a2 = a2n; a3 = a3n;
            w0 = w0n; w1 = w1n; w2 = w2n; w3 = w3n;
        }
        MAC1(a0.x, a1.x, a2.x, a3.x, w0)
        MAC1(a0.y, a1.y, a2.y, a3.y, w1)
        MAC1(a0.z, a1.z, a2.z, a3.z, w2)
        MAC1(a0.w, a1.w, a2.w, a3.w, w3)

        float4 bb = *(const float4*)(b1 + c0);
        #pragma unroll
        for (int j = 0; j < 4; ++j) {
            float4 g;
            g.x = gelu32(acc[j][0] + bb.x);
            g.y = gelu32(acc[j][1] + bb.y);
            g.z = gelu32(acc[j][2] + bb.z);
            g.w = gelu32(acc[j][3] + bb.w);
            *(float4*)&h1s[(r0 + j) * HD1 + c0] = g;
        }
    }
    __syncthreads();

    // ---------- GEMM2: (16x512)@(512x384)+b2, gelu -> h2s ----------
    {
        const int c0 = cg * 3;
        float acc[4][3];
        #pragma unroll
        for (int j = 0; j < 4; ++j)
            #pragma unroll
            for (int c = 0; c < 3; ++c) acc[j][c] = 0.f;

        const float* hr0 = h1s + r0 * HD1;
        const float* hr1 = hr0 + HD1;
        const float* hr2 = hr1 + HD1;
        const float* hr3 = hr2 + HD1;
        const float* wp  = W2 + c0;

        float4 a0 = *(const float4*)(hr0);
        float4 a1 = *(const float4*)(hr1);
        float4 a2 = *(const float4*)(hr2);
        float4 a3 = *(const float4*)(hr3);
        float wa0 = wp[0],        wa1 = wp[1],        wa2 = wp[2];
        float wb0 = wp[HD2],      wb1 = wp[HD2+1],    wb2 = wp[HD2+2];
        float wc0 = wp[2*HD2],    wc1 = wp[2*HD2+1],  wc2 = wp[2*HD2+2];
        float wd0 = wp[3*HD2],    wd1 = wp[3*HD2+1],  wd2 = wp[3*HD2+2];

        for (int k = 4; k < HD1; k += 4) {
            wp += 4 * HD2;
            float4 a0n = *(const float4*)(hr0 + k);
            float4 a1n = *(const float4*)(hr1 + k);
            float4 a2n = *(const float4*)(hr2 + k);
            float4 a3n = *(const float4*)(hr3 + k);
            float na0 = wp[0],       na1 = wp[1],       na2 = wp[2];
            float nb0 = wp[HD2],     nb1 = wp[HD2+1],   nb2 = wp[HD2+2];
            float nc0 = wp[2*HD2],   nc1 = wp[2*HD2+1], nc2 = wp[2*HD2+2];
            float nd0 = wp[3*HD2],   nd1 = wp[3*HD2+1], nd2 = wp[3*HD2+2];
            MAC2(a0.x, a1.x, a2.x, a3.x, wa0, wa1, wa2)
            MAC2(a0.y, a1.y, a2.y, a3.y, wb0, wb1, wb2)
            MAC2(a0.z, a1.z, a2.z, a3.z, wc0, wc1, wc2)
            MAC2(a0.w, a1.w, a2.w, a3.w, wd0, wd1, wd2)
            a0 = a0n; a1 = a1n; a2 = a2n; a3 = a3n;
            wa0 = na0; wa1 = na1; wa2 = na2;
            wb0 = nb0; wb1 = nb1; wb2 = nb2;
            wc0 = nc0; wc1 = nc1; wc2 = nc2;
            wd0 = nd0; wd1 = nd1; wd2 = nd2;
        }
        MAC2(a0.x, a1.x, a2.x, a3.x, wa0, wa1, wa2)
        MAC2(a0.y, a1.y, a2.y, a3.y, wb0, wb1, wb2)
        MAC2(a0.z, a1.z, a2.z, a3.z, wc0, wc1, wc2)
        MAC2(a0.w, a1.w, a2.w, a3.w, wd0, wd1, wd2)

        float b0 = b2[c0], b1v = b2[c0 + 1], b2v = b2[c0 + 2];
        #pragma unroll
        for (int j = 0; j < 4; ++j) {
            h2s[(r0 + j) * HD2 + c0    ] = gelu32(acc[j][0] + b0);
            h2s[(r0 + j) * HD2 + c0 + 1] = gelu32(acc[j][1] + b1v);
            h2s[(r0 + j) * HD2 + c0 + 2] = gelu32(acc[j][2] + b2v);
        }
    }
    __syncthreads();

    // ---------- GEMM3: (16x384)@(384x256)+b3 -> encs (aliases h1) ----------
    {
        const int c0 = cg << 1;
        float acc[4][2];
        #pragma unroll
        for (int j = 0; j < 4; ++j)
            #pragma unroll
            for (int c = 0; c < 2; ++c) acc[j][c] = 0.f;

        const float* hr0 = h2s + r0 * HD2;
        const float* hr1 = hr0 + HD2;
        const float* hr2 = hr1 + HD2;
        const float* hr3 = hr2 + HD2;
        const float* wp  = W3 + c0;

        float4 a0 = *(const float4*)(hr0);
        float4 a1 = *(const float4*)(hr1);
        float4 a2 = *(const float4*)(hr2);
        float4 a3 = *(const float4*)(hr3);
        float wa0 = wp[0],     wa1 = wp[1];
        float wb0 = wp[TGT],   wb1 = wp[TGT+1];
        float wc0 = wp[2*TGT], wc1 = wp[2*TGT+1];
        float wd0 = wp[3*TGT], wd1 = wp[3*TGT+1];

        for (int k = 4; k < HD2; k += 4) {
            wp += 4 * TGT;
            float4 a0n = *(const float4*)(hr0 + k);
            float4 a1n = *(const float4*)(hr1 + k);
            float4 a2n = *(const float4*)(hr2 + k);
            float4 a3n = *(const float4*)(hr3 + k);
            float na0 = wp[0],     na1 = wp[1];
            float nb0 = wp[TGT],   nb1 = wp[TGT+1];
            float nc0 = wp[2*TGT], nc1 = wp[2*TGT+1];
            float nd0 = wp[3*TGT], nd1 = wp[3*TGT+1];
            MAC3(a0.x, a1.x, a2.x, a3.x, wa0, wa1)
            MAC3(a0.y, a1.y, a2.y, a3.y, wb0, wb1)
            MAC3(a0.z, a1.z, a2.z, a3.z, wc0, wc1)
            MAC3(a0.w, a1.w, a2.w, a3.w, wd0, wd1)
            a0 = a0n; a1 = a1n; a2 = a2n; a3 = a3n;
            wa0 = na0; wa1 = na1; wb0 = nb0; wb1 = nb1;
            wc0 = nc0; wc1 = nc1; wd0 = nd0; wd1 = nd1;
        }
        MAC3(a0.x, a1.x, a2.x, a3.x, wa0, wa1)
        MAC3(a0.y, a1.y, a2.y, a3.y, wb0, wb1)
        MAC3(a0.z, a1.z, a2.z, a3.z, wc0, wc1)
        MAC3(a0.w, a1.w, a2.w, a3.w, wd0, wd1)

        float b0 = b3[c0], b1v = b3[c0 + 1];
        #pragma unroll
        for (int j = 0; j < 4; ++j) {
            encs[(r0 + j) * TGT + c0    ] = acc[j][0] + b0;
            encs[(r0 + j) * TGT + c0 + 1] = acc[j][1] + b1v;
        }
    }
    __syncthreads();

    // ---------- PQ: f32 argmin + top-2 margin (unchanged, TAU proven) ----
    {
        const int r = t >> 5;
        const int s = (t >> 1) & 15;
        const int half = t & 1;

        float tv[16];
        const float* ep = encs + r * TGT + s * SUBD;
        #pragma unroll
        for (int d = 0; d < 16; ++d) tv[d] = -2.0f * ep[d];

        const float* cbS = cbs + (size_t)s * KCODE * SUBD;
        const float* cbH = cbS + half * 128 * SUBD;

        float l1 = 3.402823466e38f, l2 = 3.402823466e38f;
        int li = 0;
        for (int kk = 0; kk < 128; ++kk) {
            const float4* cp = (const float4*)(cbH + kk * SUBD);
            float4 c0 = cp[0], c1 = cp[1], c2 = cp[2], c3 = cp[3];
            float d0 = c0.x*(c0.x+tv[0]) + c0.y*(c0.y+tv[1]) + c0.z*(c0.z+tv[2]) + c0.w*(c0.w+tv[3]);
            float d1 = c1.x*(c1.x+tv[4]) + c1.y*(c1.y+tv[5]) + c1.z*(c1.z+tv[6]) + c1.w*(c1.w+tv[7]);
            float d2 = c2.x*(c2.x+tv[8]) + c2.y*(c2.y+tv[9]) + c2.z*(c2.z+tv[10]) + c2.w*(c2.w+tv[11]);
            float d3 = c3.x*(c3.x+tv[12]) + c3.y*(c3.y+tv[13]) + c3.z*(c3.z+tv[14]) + c3.w*(c3.w+tv[15]);
            float dist = (d0 + d1) + (d2 + d3);
            if (dist < l1)      { l2 = l1; l1 = dist; li = kk; }
            else if (dist < l2) { l2 = dist; }
        }
        int idx = li + half * 128;

        float o1 = __shfl_xor(l1, 1);
        float o2 = __shfl_xor(l2, 1);
        int   oi = __shfl_xor(idx, 1);
        float g1, g2; int gi;
        if (o1 < l1)      { g1 = o1; gi = oi; g2 = fminf(l1, o2); }
        else if (o1 > l1) { g1 = l1; gi = idx; g2 = fminf(o1, l2); }
        else              { g1 = l1; gi = (oi < idx) ? oi : idx; g2 = l1; }

        bool flagged = (g2 - g1) < TAU;
        unsigned long long mask = __ballot(flagged);
        if ((t & 31) == 0) {
            unsigned rm = (unsigned)(mask >> (t & 32));
            if (rm) {
                unsigned p = atomicAdd(cnt, 1u);
                if (p < cap) wl[p] = (unsigned)(row0 + r);
            }
        }

        const float4* sp = (const float4*)(cbS + gi * SUBD);
        float* op = out + (row0 + r) * TGT + s * SUBD;
        if (half == 0) {
            ((float4*)op)[0] = sp[0];
            ((float4*)op)[1] = sp[1];
        } else {
            ((float4*)op)[2] = sp[2];
            ((float4*)op)[3] = sp[3];
        }
    }
}

// ---------------------------------------------------------------------------
// Kernel B: batched f64 recompute of flagged rows — round-4's proven kernel
// (8 rows/block, 4-row W reuse, absmax=0 on all 65536 rows) with row-gather
// from the worklist. Grid-stride over 8-row tiles.
// ---------------------------------------------------------------------------
__global__ __launch_bounds__(NT_B) void fixup_f64_batch(
    const float* __restrict__ x,
    const float* __restrict__ W1, const float* __restrict__ b1,
    const float* __restrict__ W2, const float* __restrict__ b2,
    const float* __restrict__ W3, const float* __restrict__ b3,
    const float* __restrict__ cbs,
    float* __restrict__ out,
    const unsigned* __restrict__ cnt, const unsigned* __restrict__ wl,
    unsigned cap)
{
    __shared__ double lds[RPB_B * HD1 + RPB_B * HD2];   // 56KB
    __shared__ unsigned rowids[RPB_B];
    double* h1s  = lds;
    double* h2s  = lds + RPB_B * HD1;
    double* encs = lds;   // aliases h1

    const int t = threadIdx.x;
    unsigned n = *cnt;
    if (n > cap) n = cap;
    const unsigned ntiles = (n + RPB_B - 1) / RPB_B;

    for (unsigned tile = blockIdx.x; tile < ntiles; tile += gridDim.x) {
        if (t < RPB_B) {
            unsigned widx = tile * RPB_B + t;
            rowids[t] = wl[widx < n ? widx : (n - 1)];   // clamp: duplicate-safe
        }
        __syncthreads();

        // ---------- GEMM1 (f64): rows gathered ----------
        {
            const int rg = t >> 7, cgv = t & 127;
            const int c0 = cgv << 2;
            const int r0v = rg << 2;
            double acc[4][4];
            #pragma unroll
            for (int j = 0; j < 4; ++j)
                #pragma unroll
                for (int c = 0; c < 4; ++c) acc[j][c] = 0.0;

            const float* xr0 = x + (size_t)rowids[r0v + 0] * IN_DIM;
            const float* xr1 = x + (size_t)rowids[r0v + 1] * IN_DIM;
            const float* xr2 = x + (size_t)rowids[r0v + 2] * IN_DIM;
            const float* xr3 = x + (size_t)rowids[r0v + 3] * IN_DIM;
            const float* wp  = W1 + c0;

            for (int k = 0; k < IN_DIM; k += 4) {
                float4 a0 = *(const float4*)(xr0 + k);
                float4 a1 = *(const float4*)(xr1 + k);
                float4 a2 = *(const float4*)(xr2 + k);
                float4 a3 = *(const float4*)(xr3 + k);
                #pragma unroll
                for (int kk = 0; kk < 4; ++kk) {
                    float4 w = *(const float4*)(wp);
                    wp += HD1;
                    double w0 = (double)w.x, w1 = (double)w.y;
                    double w2 = (double)w.z, w3 = (double)w.w;
                    double av0 = (double)((const float*)&a0)[kk];
                    double av1 = (double)((const float*)&a1)[kk];
                    double av2 = (double)((const float*)&a2)[kk];
                    double av3 = (double)((const float*)&a3)[kk];
                    acc[0][0] = fma(av0, w0, acc[0][0]); acc[0][1] = fma(av0, w1, acc[0][1]);
                    acc[0][2] = fma(av0, w2, acc[0][2]); acc[0][3] = fma(av0, w3, acc[0][3]);
                    acc[1][0] = fma(av1, w0, acc[1][0]); acc[1][1] = fma(av1, w1, acc[1][1]);
                    acc[1][2] = fma(av1, w2, acc[1][2]); acc[1][3] = fma(av1, w3, acc[1][3]);
                    acc[2][0] = fma(av2, w0, acc[2][0]); acc[2][1] = fma(av2, w1, acc[2][1]);
                    acc[2][2] = fma(av2, w2, acc[2][2]); acc[2][3] = fma(av2, w3, acc[2][3]);
                    acc[3][0] = fma(av3, w0, acc[3][0]); acc[3][1] = fma(av3, w1, acc[3][1]);
                    acc[3][2] = fma(av3, w2, acc[3][2]); acc[3][3] = fma(av3, w3, acc[3][3]);
                }
            }
            double bb[4];
            #pragma unroll
            for (int c = 0; c < 4; ++c) bb[c] = (double)b1[c0 + c];
            #pragma unroll
            for (int j = 0; j < 4; ++j)
                #pragma unroll
                for (int c = 0; c < 4; ++c)
                    h1s[(r0v + j) * HD1 + c0 + c] = gelu64(acc[j][c] + bb[c]);
        }
        __syncthreads();

        // ---------- GEMM2 (f64) ----------
        {
            const int rg = t >> 7, cgv = t & 127;
            const int c0 = cgv * 3;
            const int r0v = rg << 2;
            double acc[4][3];
            #pragma unroll
            for (int j = 0; j < 4; ++j)
                #pragma unroll
                for (int c = 0; c < 3; ++c) acc[j][c] = 0.0;

            const double* hr0 = h1s + r0v * HD1;
            const double* hr1 = hr0 + HD1;
            const double* hr2 = hr1 + HD1;
            const double* hr3 = hr2 + HD1;
            const float* wp = W2 + c0;

            for (int k = 0; k < HD1; k += 2) {
                double2 a0 = *(const double2*)(hr0 + k);
                double2 a1 = *(const double2*)(hr1 + k);
                double2 a2 = *(const double2*)(hr2 + k);
                double2 a3 = *(const double2*)(hr3 + k);
                #pragma unroll
                for (int kk = 0; kk < 2; ++kk) {
                    double w0 = (double)wp[0];
                    double w1 = (double)wp[1];
                    double w2 = (double)wp[2];
                    wp += HD2;
                    double av0 = kk ? a0.y : a0.x;
                    double av1 = kk ? a1.y : a1.x;
                    double av2 = kk ? a2.y : a2.x;
                    double av3 = kk ? a3.y : a3.x;
                    acc[0][0] = fma(av0, w0, acc[0][0]); acc[0][1] = fma(av0, w1, acc[0][1]); acc[0][2] = fma(av0, w2, acc[0][2]);
                    acc[1][0] = fma(av1, w0, acc[1][0]); acc[1][1] = fma(av1, w1, acc[1][1]); acc[1][2] = fma(av1, w2, acc[1][2]);
                    acc[2][0] = fma(av2, w0, acc[2][0]); acc[2][1] = fma(av2, w1, acc[2][1]); acc[2][2] = fma(av2, w2, acc[2][2]);
                    acc[3][0] = fma(av3, w0, acc[3][0]); acc[3][1] = fma(av3, w1, acc[3][1]); acc[3][2] = fma(av3, w2, acc[3][2]);
                }
            }
            double bb[3];
            #pragma unroll
            for (int c = 0; c < 3; ++c) bb[c] = (double)b2[c0 + c];
            #pragma unroll
            for (int j = 0; j < 4; ++j)
                #pragma unroll
                for (int c = 0; c < 3; ++c)
                    h2s[(r0v + j) * HD2 + c0 + c] = gelu64(acc[j][c] + bb[c]);
        }
        __syncthreads();

        // ---------- GEMM3 (f64) -> encs ----------
        {
            const int rg = t >> 7, cgv = t & 127;
            const int c0 = cgv << 1;
            const int r0v = rg << 2;
            double acc[4][2];
            #pragma unroll
            for (int j = 0; j < 4; ++j)
                #pragma unroll
                for (int c = 0; c < 2; ++c) acc[j][c] = 0.0;

            const double* hr0 = h2s + r0v * HD2;
            const double* hr1 = hr0 + HD2;
            const double* hr2 = hr1 + HD2;
            const double* hr3 = hr2 + HD2;
            const float* wp = W3 + c0;

            for (int k = 0; k < HD2; k += 2) {
                double2 a0 = *(const double2*)(hr0 + k);
                double2 a1 = *(const double2*)(hr1 + k);
                double2 a2 = *(const double2*)(hr2 + k);
                double2 a3 = *(const double2*)(hr3 + k);
                #pragma unroll
                for (int kk = 0; kk < 2; ++kk) {
                    double w0 = (double)wp[0];
                    double w1 = (double)wp[1];
                    wp += TGT;
                    double av0 = kk ? a0.y : a0.x;
                    double av1 = kk ? a1.y : a1.x;
                    double av2 = kk ? a2.y : a2.x;
                    double av3 = kk ? a3.y : a3.x;
                    acc[0][0] = fma(av0, w0, acc[0][0]); acc[0][1] = fma(av0, w1, acc[0][1]);
                    acc[1][0] = fma(av1, w0, acc[1][0]); acc[1][1] = fma(av1, w1, acc[1][1]);
                    acc[2][0] = fma(av2, w0, acc[2][0]); acc[2][1] = fma(av2, w1, acc[2][1]);
                    acc[3][0] = fma(av3, w0, acc[3][0]); acc[3][1] = fma(av3, w1, acc[3][1]);
                }
            }
            double bb[2];
            #pragma unroll
            for (int c = 0; c < 2; ++c) bb[c] = (double)b3[c0 + c];
            #pragma unroll
            for (int j = 0; j < 4; ++j)
                #pragma unroll
                for (int c = 0; c < 2; ++c)
                    encs[(r0v + j) * TGT + c0 + c] = acc[j][c] + bb[c];
        }
        __syncthreads();

        // ---------- PQ (f64), split-k across lane pairs ----------
        {
            const int r = t >> 5;
            const int s = (t >> 1) & 15;
            const int half = t & 1;

            double e[16];
            const double* ep = encs + r * TGT + s * SUBD;
            #pragma unroll
            for (int d = 0; d < 16; ++d) e[d] = ep[d];

            const float* cbS = cbs + (size_t)s * KCODE * SUBD;
            const float* cbH = cbS + half * 128 * SUBD;

            double best = 1.0e300;
            int bi = 0;
            for (int kk = 0; kk < 128; ++kk) {
                const float4* cp = (const float4*)(cbH + kk * SUBD);
                float4 c0 = cp[0], c1 = cp[1], c2 = cp[2], c3 = cp[3];
                double dist = 0.0, dd;
                dd = (double)c0.x - e[0];  dist = fma(dd, dd, dist);
                dd = (double)c0.y - e[1];  dist = fma(dd, dd, dist);
                dd = (double)c0.z - e[2];  dist = fma(dd, dd, dist);
                dd = (double)c0.w - e[3];  dist = fma(dd, dd, dist);
                dd = (double)c1.x - e[4];  dist = fma(dd, dd, dist);
                dd = (double)c1.y - e[5];  dist = fma(dd, dd, dist);
                dd = (double)c1.z - e[6];  dist = fma(dd, dd, dist);
                dd = (double)c1.w - e[7];  dist = fma(dd, dd, dist);
                dd = (double)c2.x - e[8];  dist = fma(dd, dd, dist);
                dd = (double)c2.y - e[9];  dist = fma(dd, dd, dist);
                dd = (double)c2.z - e[10]; dist = fma(dd, dd, dist);
                dd = (double)c2.w - e[11]; dist = fma(dd, dd, dist);
                dd = (double)c3.x - e[12]; dist = fma(dd, dd, dist);
                dd = (double)c3.y - e[13]; dist = fma(dd, dd, dist);
                dd = (double)c3.z - e[14]; dist = fma(dd, dd, dist);
                dd = (double)c3.w - e[15]; dist = fma(dd, dd, dist);
                if (dist < best) { best = dist; bi = kk; }
            }
            bi += half * 128;

            double obest = __shfl_xor(best, 1);
            int    obi   = __shfl_xor(bi, 1);
            if (obest < best || (obest == best && obi < bi)) { best = obest; bi = obi; }

            const float4* sp = (const float4*)(cbS + bi * SUBD);
            float* op = out + (size_t)rowids[r] * TGT + s * SUBD;
            if (half == 0) {
                ((float4*)op)[0] = sp[0];
                ((float4*)op)[1] = sp[1];
            } else {
                ((float4*)op)[2] = sp[2];
                ((float4*)op)[3] = sp[3];
            }
        }
        __syncthreads();   // protect h1s/rowids reuse across tiles
    }
}

extern "C" void kernel_launch(void* const* d_in, const int* in_sizes, int n_in,
                              void* d_out, int out_size, void* d_ws, size_t ws_size,
                              hipStream_t stream) {
    const float* x   = (const float*)d_in[0];
    const float* W1  = (const float*)d_in[1];
    const float* b1  = (const float*)d_in[2];
    const float* W2  = (const float*)d_in[3];
    const float* b2  = (const float*)d_in[4];
    const float* W3  = (const float*)d_in[5];
    const float* b3  = (const float*)d_in[6];
    const float* cbs = (const float*)d_in[7];
    float* out = (float*)d_out;

    const int B = in_sizes[0] / IN_DIM;   // 65536
    unsigned* cnt = (unsigned*)d_ws;
    unsigned* wl  = cnt + 1;
    size_t cap_sz = (ws_size / sizeof(unsigned)) - 1;
    unsigned cap = (unsigned)(cap_sz > 65536 ? 65536 : cap_sz);

    hipMemsetAsync(d_ws, 0, sizeof(unsigned), stream);  // zero the counter
    hipLaunchKernelGGL(mlp_pq_f32, dim3(B / RPB), dim3(NT_A), 0, stream,
                       x, W1, b1, W2, b2, W3, b3, cbs, out, cnt, wl, cap);
    hipLaunchKernelGGL(fixup_f64_batch, dim3(2048), dim3(NT_B), 0, stream,
                       x, W1, b1, W2, b2, W3, b3, cbs, out, cnt, wl, cap);
}